// Round 10
// baseline (1237.468 us; speedup 1.0000x reference)
//
#include <hip/hip_runtime.h>
#include <hip/hip_bf16.h>

#define AS1 __attribute__((address_space(1)))
#define AS3 __attribute__((address_space(3)))

typedef __attribute__((ext_vector_type(4))) float f32x4;
typedef __attribute__((ext_vector_type(8))) short b16x8;     // 8 bf16 (4 VGPRs) MFMA operand
typedef __attribute__((ext_vector_type(8))) unsigned short u16x8;
typedef unsigned short u16;

static __device__ __forceinline__ u16 f2b(float f) {
  return __builtin_bit_cast(u16, __float2bfloat16(f));
}
static __device__ __forceinline__ float b2f(u16 u) {
  unsigned v = ((unsigned)u) << 16;
  return __builtin_bit_cast(float, v);
}
static __device__ __forceinline__ unsigned cvtpk(float a, float b) {
  unsigned r;  // r.lo = bf16(a), r.hi = bf16(b)
  asm("v_cvt_pk_bf16_f32 %0, %1, %2" : "=v"(r) : "v"(a), "v"(b));
  return r;
}
static __device__ __forceinline__ void gl2lds16(const u16* g, u16* l) {
  __builtin_amdgcn_global_load_lds((const AS1 void*)g, (AS3 void*)l, 16, 0, 0);
}

// ---------------- fp32 -> bf16 convert, 8 elems/thread ----------------
__global__ void k_cvt(const float* __restrict__ s, u16* __restrict__ d, long n) {
  long i = ((long)blockIdx.x * 256 + threadIdx.x) * 8;
  if (i >= n) return;
  float4 a = *(const float4*)(s + i);
  float4 b = *(const float4*)(s + i + 4);
  u16x8 o;
  o[0] = f2b(a.x); o[1] = f2b(a.y); o[2] = f2b(a.z); o[3] = f2b(a.w);
  o[4] = f2b(b.x); o[5] = f2b(b.y); o[6] = f2b(b.z); o[7] = f2b(b.w);
  *(u16x8*)(d + i) = o;
}

// ------- RPE tables: out[h][r(240)][d(32)] = bf16(src[(d*32+h)*225 + r]), r>=225 -> 0 -------
__global__ void k_rpe(const float* __restrict__ rq, const float* __restrict__ rk,
                      u16* __restrict__ oq, u16* __restrict__ ok) {
  int h = blockIdx.y;
  int r = blockIdx.x * 8 + (threadIdx.x >> 5);
  int d = threadIdx.x & 31;
  const float* s = blockIdx.z ? rk : rq;
  u16* o = blockIdx.z ? ok : oq;
  float v = (r < 225) ? s[(d * 32 + h) * 225 + r] : 0.f;
  o[(h * 240 + r) * 32 + d] = f2b(v);
}

// ------- 256x256 tile GEMM, BK=32, 4-deep counted-vmcnt pipeline, 2-phase K-step ----
// (R5 configuration: best measured 433-436 us, refcheck'd.)
// vmcnt LEDGER: prologue STG(0,1,2)=12 out -> vmcnt(8): tile0 landed, 1,2 in flight.
//   End of step t: vmcnt(8) drains tile t+1 (FIFO) -> barrier. Tail 28->8, 29->4, 30->0.
//   WAR: STG(t+3) targets buf[(t-1)&3]; readers drained before step t-1's final barrier.
// MODE 0: qkv epilogue -> per-head layout (+bias, V transposed). MODE 1: fp32 out + bias.
template <int MODE>
__global__ __launch_bounds__(512) void k_gemm(
    const u16* __restrict__ A, const u16* __restrict__ Bw,
    const float* __restrict__ b0, const float* __restrict__ b1, const float* __restrict__ b2,
    u16* __restrict__ oq, float* __restrict__ of, int m_base) {
  __shared__ alignas(16) u16 lds[4][16384];  // [buf][A:0..8191 | B:8192..16383]
  const int tid = threadIdx.x;
  const int l = tid & 63, w = tid >> 6;
  const int lo = l & 15, hi = l >> 4;
  const int wr = w >> 2, wc = w & 3;

  // bijective XCD swizzle (nwg % 8 == 0 for all grids)
  const int nbx = gridDim.x;
  const int nb = nbx * gridDim.y;
  const int bid = blockIdx.y * nbx + blockIdx.x;
  const int ord = (bid & 7) * (nb >> 3) + (bid >> 3);
  const int tn = (ord % nbx) * 256, tm = m_base + (ord / nbx) * 256;

  // staging lane map: pre-swizzled global source, linear LDS dest (lane*16B)
  const int sl = (tid & 7) ^ ((tid >> 3) & 7);   // logical slot this lane's dest holds
  const int srow = 2 * (tid >> 3) + (sl >> 2);   // row within half-tile (q=0); q=1 adds 128
  const int scol = (sl & 3) * 8;
  const u16* gA = A + (size_t)(tm + srow) * 1024 + scol;
  const u16* gB = Bw + (size_t)(tn + srow) * 1024 + scol;
  u16* dst = &lds[0][0] + tid * 8;

  // fragment-read lane constants (same involution)
  const int p7 = (lo >> 1) & 7;
  const int slr = ((lo & 1) * 4 + hi) ^ p7;
  const int aoff = wr * 4096 + (lo >> 1) * 64 + slr * 8;
  const int boff = 8192 + wc * 2048 + (lo >> 1) * 64 + slr * 8;

  f32x4 acc[8][4];
#pragma unroll
  for (int i = 0; i < 8; ++i)
#pragma unroll
    for (int j = 0; j < 4; ++j) acc[i][j] = (f32x4){0.f, 0.f, 0.f, 0.f};

  b16x8 af[8], bf[4];

#define STG_A(t) { const int kc = (t) * 32; u16* d = dst + ((t) & 3) * 16384; \
    gl2lds16(gA + kc, d);  gl2lds16(gA + 131072 + kc, d + 4096); }
#define STG_B(t) { const int kc = (t) * 32; u16* d = dst + ((t) & 3) * 16384; \
    gl2lds16(gB + kc, d + 8192);  gl2lds16(gB + 131072 + kc, d + 12288); }
#define PHA(bi) { const u16* _b = &lds[0][0] + (bi) * 16384; \
    _Pragma("unroll") for (int _i = 0; _i < 4; ++_i) af[_i] = *(const b16x8*)(_b + aoff + _i * 512); \
    _Pragma("unroll") for (int _j = 0; _j < 4; ++_j) bf[_j] = *(const b16x8*)(_b + boff + _j * 512); \
    __builtin_amdgcn_s_barrier(); \
    asm volatile("s_waitcnt lgkmcnt(0)" ::: "memory"); \
    __builtin_amdgcn_sched_barrier(0); \
    __builtin_amdgcn_s_setprio(1); \
    _Pragma("unroll") for (int _i = 0; _i < 4; ++_i) \
    _Pragma("unroll") for (int _j = 0; _j < 4; ++_j) \
      acc[_i][_j] = __builtin_amdgcn_mfma_f32_16x16x32_bf16(af[_i], bf[_j], acc[_i][_j], 0, 0, 0); \
    __builtin_amdgcn_s_setprio(0); \
    __builtin_amdgcn_s_barrier(); }
#define PHB(bi) { const u16* _b = &lds[0][0] + (bi) * 16384; \
    _Pragma("unroll") for (int _i = 4; _i < 8; ++_i) af[_i] = *(const b16x8*)(_b + aoff + _i * 512); \
    __builtin_amdgcn_s_barrier(); \
    asm volatile("s_waitcnt lgkmcnt(0)" ::: "memory"); \
    __builtin_amdgcn_sched_barrier(0); \
    __builtin_amdgcn_s_setprio(1); \
    _Pragma("unroll") for (int _i = 4; _i < 8; ++_i) \
    _Pragma("unroll") for (int _j = 0; _j < 4; ++_j) \
      acc[_i][_j] = __builtin_amdgcn_mfma_f32_16x16x32_bf16(af[_i], bf[_j], acc[_i][_j], 0, 0, 0); \
    __builtin_amdgcn_s_setprio(0); }
#define WV(n) { asm volatile("s_waitcnt vmcnt(" #n ")" ::: "memory"); \
    __builtin_amdgcn_s_barrier(); asm volatile("" ::: "memory"); }

  STG_A(0) STG_B(0) STG_A(1) STG_B(1) STG_A(2) STG_B(2)
  asm volatile("s_waitcnt vmcnt(8)" ::: "memory");  // tile 0 landed; 1,2 in flight
  __builtin_amdgcn_s_barrier();
  asm volatile("" ::: "memory");

#pragma unroll 4
  for (int kt = 0; kt < 28; ++kt) {
    STG_A(kt + 3)
    PHA(kt & 3)
    STG_B(kt + 3)
    PHB(kt & 3)
    WV(8)             // tile kt+1 drained; kt+2,kt+3 (8 loads) in flight
  }
  STG_A(31) PHA(0) STG_B(31) PHB(0) WV(8)   // step 28
  PHA(1) PHB(1) WV(4)                       // step 29
  PHA(2) PHB(2) WV(0)                       // step 30
  PHA(3) PHB(3)                             // step 31
#undef STG_A
#undef STG_B
#undef PHA
#undef PHB
#undef WV

  if (MODE == 0) {
    const size_t G = 67108864;  // elements per q/k/v plane
    const int g = tn >> 10;     // 0:q 1:k 2:v (256 | 1024 -> uniform per block)
    const float* bias = (g == 0) ? b0 : (g == 1) ? b1 : b2;
    const int nn0 = (tn & 1023) + wc * 64;
#pragma unroll
    for (int j = 0; j < 4; ++j) {
      const int nn = nn0 + j * 16 + lo;
      const float bv = bias[nn];
      const int h = nn >> 5, hd = nn & 31;
      if (g < 2) {
#pragma unroll
        for (int i = 0; i < 8; ++i) {
          const int m0 = tm + wr * 128 + i * 16 + hi * 4;  // row = (l>>4)*4 + reg
          const int b = m0 >> 6, s0 = m0 & 63;
          const size_t base = (size_t)g * G + ((size_t)(b * 32 + h) * 64 + s0) * 32 + hd;
#pragma unroll
          for (int r = 0; r < 4; ++r) oq[base + (size_t)r * 32] = f2b(acc[i][j][r] + bv);
        }
      } else {
#pragma unroll
        for (int i = 0; i < 8; ++i) {
          const int m0 = tm + wr * 128 + i * 16 + hi * 4;
          const int b = m0 >> 6, s0 = m0 & 63;
          ushort4 pk;
          pk.x = f2b(acc[i][j][0] + bv);
          pk.y = f2b(acc[i][j][1] + bv);
          pk.z = f2b(acc[i][j][2] + bv);
          pk.w = f2b(acc[i][j][3] + bv);
          *(ushort4*)(oq + 2 * G + ((size_t)(b * 32 + h) * 32 + hd) * 64 + s0) = pk;
        }
      }
    }
  } else {
#pragma unroll
    for (int j = 0; j < 4; ++j) {
      const int n = tn + wc * 64 + j * 16 + lo;
      const float bv = b0[n];
#pragma unroll
      for (int i = 0; i < 8; ++i) {
        const int m0 = tm + wr * 128 + i * 16 + hi * 4;
#pragma unroll
        for (int r = 0; r < 4; ++r) of[(size_t)(m0 + r) * 1024 + n] = acc[i][j][r] + bv;
      }
    }
  }
}

// ---------------- attention (R10: swapped layout; softmax = 4 shuffles) ----------------
// One (b,h) per 256-thread block; wave w owns q-rows [w*16, w*16+16).
// QK^T computed SWAPPED: s0[kt] = mfma(K_tile, Q) -> lane (lo,hi) holds
// S[k=kt*16+hi*4+r][q=w*16+lo]. Lane has 16 of 64 k-values for its q; the other 48 live in
// the 3 sibling lanes (same lo, hi'=hi^{1,2,3}) -> softmax reduce = shfl_xor 16,32 for max
// and sum (4 shuffles total; R9 BUG: omitted these -> partial-sum normalization, absmax 0.95).
// Boards: packed [q>>2|k>>2][col(240)][q&3|k&3] u16, b64 stores. Gathers hoisted: rel(q,k0+r)
// = rel0 - r -> Bq at g[-4r] (eq fixed), Bk at g[-3r] (elem slot = r).
// P exchange: normalize in-reg, cvt_pk pairs, XOR-swizzled pl rows (blk' = blk ^ (q&7)),
// 4 ds_write_b64 + 2 ds_read_b128, same-wave RAW. Exactly ONE __syncthreads.
__global__ __launch_bounds__(256) void k_attn(
    const u16* __restrict__ qkv, const u16* __restrict__ rq,
    const u16* __restrict__ rk, u16* __restrict__ att) {
  __shared__ alignas(16) u16 board[16 * 240 * 4];  // 30720 B
  __shared__ alignas(16) u16 pl[64 * 72];          // 9216 B, XOR-swizzled 16B blocks
  const int l = threadIdx.x & 63, w = threadIdx.x >> 6;
  const int lo = l & 15, hi = l >> 4;
  const int b = blockIdx.x, h = blockIdx.y;
  const size_t G = 67108864;
  const u16* qp = qkv + (size_t)(b * 32 + h) * 2048;          // [64][32]
  const u16* kp = qkv + G + (size_t)(b * 32 + h) * 2048;      // [64][32]
  const u16* vp = qkv + 2 * G + (size_t)(b * 32 + h) * 2048;  // V^T [32][64]

  // fragments: qf = Q[w*16+lo][hi*8..]; kfa = K[w*16+lo][hi*8..] (Bk A-operand, direct load
  // -- NOT kf[w]: runtime-indexed ext_vector arrays go to scratch, rule #20)
  b16x8 qf = *(const b16x8*)(qp + (w * 16 + lo) * 32 + hi * 8);
  b16x8 kfa = *(const b16x8*)(kp + (w * 16 + lo) * 32 + hi * 8);
  // hoisted V fragments (B-operands for PV)
  b16x8 v00 = *(const b16x8*)(vp + lo * 64 + hi * 8);
  b16x8 v01 = *(const b16x8*)(vp + lo * 64 + 32 + hi * 8);
  b16x8 v10 = *(const b16x8*)(vp + (16 + lo) * 64 + hi * 8);
  b16x8 v11 = *(const b16x8*)(vp + (16 + lo) * 64 + 32 + hi * 8);

  // Phase 1: swapped QK^T: s0[kt][r] = S[k=kt*16+hi*4+r][q=w*16+lo]
  f32x4 s0[4];
#pragma unroll
  for (int kt = 0; kt < 4; ++kt) {
    b16x8 kf = *(const b16x8*)(kp + (kt * 16 + lo) * 32 + hi * 8);
    f32x4 z = (f32x4){0.f, 0.f, 0.f, 0.f};
    s0[kt] = __builtin_amdgcn_mfma_f32_16x16x32_bf16(kf, qf, z, 0, 0, 0);
  }

  // Phase 2: Bq = Q @ Rq[h]^T -> board rows (w*4+hi) packed b64 (wave-private rows)
  const u16* rqh = rq + (size_t)h * 7680;  // 240*32
#pragma unroll
  for (int nt = 0; nt < 15; ++nt) {
    b16x8 rf = *(const b16x8*)(rqh + (nt * 16 + lo) * 32 + hi * 8);
    f32x4 z = (f32x4){0.f, 0.f, 0.f, 0.f};
    f32x4 c = __builtin_amdgcn_mfma_f32_16x16x32_bf16(qf, rf, z, 0, 0, 0);
    ushort4 pk;
    pk.x = f2b(c[0]); pk.y = f2b(c[1]); pk.z = f2b(c[2]); pk.w = f2b(c[3]);
    *(ushort4*)(board + (((w * 4 + hi) * 240 + nt * 16 + lo) << 2)) = pk;
  }

  // per-lane q constants
  const int q = w * 16 + lo, qi = q >> 3, qj = q & 7;
  const int rowq = w * 4 + (lo >> 2);   // board row holding q
  const int eq = lo & 3;                // element slot of q

  // Phase 3: gather Bq[q][rel(q,k)] for k = kt*16+hi*4+r (rel0-r consecutive, own-wave rows)
#pragma unroll
  for (int kt = 0; kt < 4; ++kt) {
    const int k0 = kt * 16 + hi * 4;
    const int rel0 = 15 * (qi - (k0 >> 3) + 7) + qj - (k0 & 7) + 7;
    const u16* g = board + (rowq * 240 + rel0) * 4 + eq;
    s0[kt][0] += b2f(g[0]);
    s0[kt][1] += b2f(g[-4]);
    s0[kt][2] += b2f(g[-8]);
    s0[kt][3] += b2f(g[-12]);
  }

  // Phase 4: Bk = K @ Rk[h]^T -> board rows (w*4+hi)
  const u16* rkh = rk + (size_t)h * 7680;
#pragma unroll
  for (int nt = 0; nt < 15; ++nt) {
    b16x8 rf = *(const b16x8*)(rkh + (nt * 16 + lo) * 32 + hi * 8);
    f32x4 z = (f32x4){0.f, 0.f, 0.f, 0.f};
    f32x4 c = __builtin_amdgcn_mfma_f32_16x16x32_bf16(kfa, rf, z, 0, 0, 0);
    ushort4 pk;
    pk.x = f2b(c[0]); pk.y = f2b(c[1]); pk.z = f2b(c[2]); pk.w = f2b(c[3]);
    *(ushort4*)(board + (((w * 4 + hi) * 240 + nt * 16 + lo) << 2)) = pk;
  }
  __syncthreads();  // Bk board read cross-wave below

  // Phase 5: gather Bk[k][rel(q,k)]: row = kt*4+hi, elem = r, addr = base - 3r
#pragma unroll
  for (int kt = 0; kt < 4; ++kt) {
    const int k0 = kt * 16 + hi * 4;
    const int rel0 = 15 * (qi - (k0 >> 3) + 7) + qj - (k0 & 7) + 7;
    const u16* g = board + ((kt * 4 + hi) * 240 + rel0) * 4;
    s0[kt][0] += b2f(g[0]);
    s0[kt][1] += b2f(g[-3]);
    s0[kt][2] += b2f(g[-6]);
    s0[kt][3] += b2f(g[-9]);
  }

  // Phase 6: scale + softmax over k; lane has 16 k's, siblings (xor 16,32) have the rest
  const float sc = 0.17677669529663689f;  // 1/sqrt(32)
#pragma unroll
  for (int kt = 0; kt < 4; ++kt) s0[kt] *= sc;
  float m0 = fmaxf(fmaxf(s0[0][0], s0[0][1]), fmaxf(s0[0][2], s0[0][3]));
  float m1 = fmaxf(fmaxf(s0[1][0], s0[1][1]), fmaxf(s0[1][2], s0[1][3]));
  float m2 = fmaxf(fmaxf(s0[2][0], s0[2][1]), fmaxf(s0[2][2], s0[2][3]));
  float m3 = fmaxf(fmaxf(s0[3][0], s0[3][1]), fmaxf(s0[3][2], s0[3][3]));
  float m = fmaxf(fmaxf(m0, m1), fmaxf(m2, m3));
  m = fmaxf(m, __shfl_xor(m, 16));
  m = fmaxf(m, __shfl_xor(m, 32));
  float p[4][4];
  float sum = 0.f;
#pragma unroll
  for (int kt = 0; kt < 4; ++kt)
#pragma unroll
    for (int r = 0; r < 4; ++r) {
      float e = __expf(s0[kt][r] - m);
      p[kt][r] = e;
      sum += e;
    }
  sum += __shfl_xor(sum, 16);
  sum += __shfl_xor(sum, 32);
  const float inv = 1.f / sum;

  // Phase 7: normalize, cvt_pk, write to swizzled pl (4 x ds_write_b64, own row q)
  const int key = q & 7;
  char* plrow = (char*)pl + q * 144;
#pragma unroll
  for (int kt = 0; kt < 4; ++kt) {
    uint2 pk;
    pk.x = cvtpk(p[kt][0] * inv, p[kt][1] * inv);
    pk.y = cvtpk(p[kt][2] * inv, p[kt][3] * inv);
    const int blk = 2 * kt + (hi >> 1);
    *(uint2*)(plrow + ((blk ^ key) * 16) + (hi & 1) * 8) = pk;
  }

  // Phase 8: read A-frags (2 x ds_read_b128, same-wave RAW) and PV
  b16x8 pa0 = *(const b16x8*)(plrow + ((hi ^ key) * 16));        // k = hi*8..+8
  b16x8 pa1 = *(const b16x8*)(plrow + (((4 + hi) ^ key) * 16));  // k = 32+hi*8..+8
  f32x4 o0 = (f32x4){0.f, 0.f, 0.f, 0.f}, o1 = (f32x4){0.f, 0.f, 0.f, 0.f};
  o0 = __builtin_amdgcn_mfma_f32_16x16x32_bf16(pa0, v00, o0, 0, 0, 0);
  o1 = __builtin_amdgcn_mfma_f32_16x16x32_bf16(pa0, v10, o1, 0, 0, 0);
  o0 = __builtin_amdgcn_mfma_f32_16x16x32_bf16(pa1, v01, o0, 0, 0, 0);
  o1 = __builtin_amdgcn_mfma_f32_16x16x32_bf16(pa1, v11, o1, 0, 0, 0);

  // Phase 9: write att[b][s=q'][h*32+hd]; O rows q' = w*16+hi*4+r, cols d = lo (+16)
#pragma unroll
  for (int r = 0; r < 4; ++r) {
    const int qr = w * 16 + hi * 4 + r;
    size_t base = (size_t)(b * 64 + qr) * 1024 + h * 32;
    att[base + lo] = f2b(o0[r]);
    att[base + 16 + lo] = f2b(o1[r]);
  }
}

extern "C" void kernel_launch(void* const* d_in, const int* in_sizes, int n_in,
                              void* d_out, int out_size, void* d_ws, size_t ws_size,
                              hipStream_t stream) {
  const float* x   = (const float*)d_in[0];
  const float* qw  = (const float*)d_in[1];
  const float* qb  = (const float*)d_in[2];
  const float* kw  = (const float*)d_in[3];
  const float* kb  = (const float*)d_in[4];
  const float* vw  = (const float*)d_in[5];
  const float* vb  = (const float*)d_in[6];
  const float* ow  = (const float*)d_in[7];
  const float* ob  = (const float*)d_in[8];
  const float* rqw = (const float*)d_in[9];
  const float* rkw = (const float*)d_in[10];

  // workspace layout (total 680,460,288 bytes)
  if (ws_size < 680460288ULL) return;  // diagnostic: leaves d_out zeroed -> absmax == max|ref|
  char* p = (char*)d_ws;
  u16* ws_x   = (u16*)p; p += (size_t)65536 * 1024 * 2;      // x bf16
  u16* ws_w   = (u16*)p; p += (size_t)3 * 1024 * 1024 * 2;   // qkv weights bf16 [3072][1024]
  u16* ws_wo  = (u16*)p; p += (size_t)1024 * 1024 * 2;       // out_w bf16
  u16* ws_rq  = (u16*)p; p += (size_t)32 * 240 * 32 * 2;     // Rq [h][r][d]
  u16* ws_rk  = (u16*)p; p += (size_t)32 * 240 * 32 * 2;     // Rk [h][r][d]
  u16* ws_qkv = (u16*)p; p += (size_t)3 * 67108864 * 2;      // q,k [b][h][s][hd]; v [b][h][hd][s]
  u16* ws_att = (u16*)p; p += (size_t)65536 * 1024 * 2;      // attention out [b*s][1024]

  k_cvt<<<32768, 256, 0, stream>>>(x, ws_x, 67108864L);
  k_cvt<<<512, 256, 0, stream>>>(qw, ws_w, 1048576L);
  k_cvt<<<512, 256, 0, stream>>>(kw, ws_w + 1048576, 1048576L);
  k_cvt<<<512, 256, 0, stream>>>(vw, ws_w + 2097152, 1048576L);
  k_cvt<<<512, 256, 0, stream>>>(ow, ws_wo, 1048576L);
  k_rpe<<<dim3(30, 32, 2), 256, 0, stream>>>(rqw, rkw, ws_rq, ws_rk);

  // QKV projection, split into two half-M launches (profiling visibility; nwg=1536 %8==0)
  k_gemm<0><<<dim3(12, 128), 512, 0, stream>>>(ws_x, ws_w, qb, kb, vb, ws_qkv, nullptr, 0);
  k_gemm<0><<<dim3(12, 128), 512, 0, stream>>>(ws_x, ws_w, qb, kb, vb, ws_qkv, nullptr, 32768);
  // attention: grid.x = b (fastest) so consecutive blocks reuse Rq[h]/Rk[h] in cache
  k_attn<<<dim3(1024, 32), 256, 0, stream>>>(ws_qkv, ws_rq, ws_rk, ws_att);
  // output projection: 4 n-tiles x 256 m-tiles (nwg=1024)
  k_gemm<1><<<dim3(4, 256), 512, 0, stream>>>(ws_att, ws_wo, ob, nullptr, nullptr, nullptr,
                                              (float*)d_out, 0);
}

// Round 11
// 1028.417 us; speedup vs baseline: 1.2033x; 1.2033x over previous
//
#include <hip/hip_runtime.h>
#include <hip/hip_bf16.h>

#define AS1 __attribute__((address_space(1)))
#define AS3 __attribute__((address_space(3)))

typedef __attribute__((ext_vector_type(4))) float f32x4;
typedef __attribute__((ext_vector_type(8))) short b16x8;     // 8 bf16 (4 VGPRs) MFMA operand
typedef __attribute__((ext_vector_type(8))) unsigned short u16x8;
typedef unsigned short u16;

static __device__ __forceinline__ u16 f2b(float f) {
  return __builtin_bit_cast(u16, __float2bfloat16(f));
}
static __device__ __forceinline__ float b2f(u16 u) {
  unsigned v = ((unsigned)u) << 16;
  return __builtin_bit_cast(float, v);
}
static __device__ __forceinline__ void gl2lds16(const u16* g, u16* l) {
  __builtin_amdgcn_global_load_lds((const AS1 void*)g, (AS3 void*)l, 16, 0, 0);
}

// ---------------- fp32 -> bf16 convert, 8 elems/thread ----------------
__global__ void k_cvt(const float* __restrict__ s, u16* __restrict__ d, long n) {
  long i = ((long)blockIdx.x * 256 + threadIdx.x) * 8;
  if (i >= n) return;
  float4 a = *(const float4*)(s + i);
  float4 b = *(const float4*)(s + i + 4);
  u16x8 o;
  o[0] = f2b(a.x); o[1] = f2b(a.y); o[2] = f2b(a.z); o[3] = f2b(a.w);
  o[4] = f2b(b.x); o[5] = f2b(b.y); o[6] = f2b(b.z); o[7] = f2b(b.w);
  *(u16x8*)(d + i) = o;
}

// ------- RPE tables, PRE-SWIZZLED for LDS staging (R11) -------
// Logical [h][row(240)][d(32)] bf16, rows 225..239 zero. Storage applies the GEMM involution:
// p = row>>1, slot_logical = (row&1)*4 + (d>>3), slot_storage = slot_logical ^ (p&7),
// addr_u16 = h*7680 + p*64 + slot_storage*8 + (d&7). attn stages linearly via global_load_lds
// and reads fragments with the same involution -> ~2-way LDS banks (free).
__global__ void k_rpe(const float* __restrict__ rq, const float* __restrict__ rk,
                      u16* __restrict__ oq, u16* __restrict__ ok) {
  int h = blockIdx.y;
  int r = blockIdx.x * 8 + (threadIdx.x >> 5);
  int d = threadIdx.x & 31;
  const float* s = blockIdx.z ? rk : rq;
  u16* o = blockIdx.z ? ok : oq;
  float v = (r < 225) ? s[(d * 32 + h) * 225 + r] : 0.f;
  int p = r >> 1;
  int sl = (((r & 1) << 2) + (d >> 3)) ^ (p & 7);
  o[h * 7680 + p * 64 + sl * 8 + (d & 7)] = f2b(v);
}

// ------- 256x256 tile GEMM, BK=32, 4-deep counted-vmcnt pipeline, 2-phase K-step ----
// (R5 configuration: best measured 433-436 us, refcheck'd.)
// vmcnt LEDGER: prologue STG(0,1,2)=12 out -> vmcnt(8): tile0 landed, 1,2 in flight.
//   End of step t: vmcnt(8) drains tile t+1 (FIFO) -> barrier. Tail 28->8, 29->4, 30->0.
//   WAR: STG(t+3) targets buf[(t-1)&3]; readers drained before step t-1's final barrier.
// MODE 0: qkv epilogue -> per-head layout (+bias, V transposed). MODE 1: fp32 out + bias.
template <int MODE>
__global__ __launch_bounds__(512) void k_gemm(
    const u16* __restrict__ A, const u16* __restrict__ Bw,
    const float* __restrict__ b0, const float* __restrict__ b1, const float* __restrict__ b2,
    u16* __restrict__ oq, float* __restrict__ of, int m_base) {
  __shared__ alignas(16) u16 lds[4][16384];  // [buf][A:0..8191 | B:8192..16383]
  const int tid = threadIdx.x;
  const int l = tid & 63, w = tid >> 6;
  const int lo = l & 15, hi = l >> 4;
  const int wr = w >> 2, wc = w & 3;

  // bijective XCD swizzle (nwg % 8 == 0 for all grids)
  const int nbx = gridDim.x;
  const int nb = nbx * gridDim.y;
  const int bid = blockIdx.y * nbx + blockIdx.x;
  const int ord = (bid & 7) * (nb >> 3) + (bid >> 3);
  const int tn = (ord % nbx) * 256, tm = m_base + (ord / nbx) * 256;

  // staging lane map: pre-swizzled global source, linear LDS dest (lane*16B)
  const int sl = (tid & 7) ^ ((tid >> 3) & 7);   // logical slot this lane's dest holds
  const int srow = 2 * (tid >> 3) + (sl >> 2);   // row within half-tile (q=0); q=1 adds 128
  const int scol = (sl & 3) * 8;
  const u16* gA = A + (size_t)(tm + srow) * 1024 + scol;
  const u16* gB = Bw + (size_t)(tn + srow) * 1024 + scol;
  u16* dst = &lds[0][0] + tid * 8;

  // fragment-read lane constants (same involution)
  const int p7 = (lo >> 1) & 7;
  const int slr = ((lo & 1) * 4 + hi) ^ p7;
  const int aoff = wr * 4096 + (lo >> 1) * 64 + slr * 8;
  const int boff = 8192 + wc * 2048 + (lo >> 1) * 64 + slr * 8;

  f32x4 acc[8][4];
#pragma unroll
  for (int i = 0; i < 8; ++i)
#pragma unroll
    for (int j = 0; j < 4; ++j) acc[i][j] = (f32x4){0.f, 0.f, 0.f, 0.f};

  b16x8 af[8], bf[4];

#define STG_A(t) { const int kc = (t) * 32; u16* d = dst + ((t) & 3) * 16384; \
    gl2lds16(gA + kc, d);  gl2lds16(gA + 131072 + kc, d + 4096); }
#define STG_B(t) { const int kc = (t) * 32; u16* d = dst + ((t) & 3) * 16384; \
    gl2lds16(gB + kc, d + 8192);  gl2lds16(gB + 131072 + kc, d + 12288); }
#define PHA(bi) { const u16* _b = &lds[0][0] + (bi) * 16384; \
    _Pragma("unroll") for (int _i = 0; _i < 4; ++_i) af[_i] = *(const b16x8*)(_b + aoff + _i * 512); \
    _Pragma("unroll") for (int _j = 0; _j < 4; ++_j) bf[_j] = *(const b16x8*)(_b + boff + _j * 512); \
    __builtin_amdgcn_s_barrier(); \
    asm volatile("s_waitcnt lgkmcnt(0)" ::: "memory"); \
    __builtin_amdgcn_sched_barrier(0); \
    __builtin_amdgcn_s_setprio(1); \
    _Pragma("unroll") for (int _i = 0; _i < 4; ++_i) \
    _Pragma("unroll") for (int _j = 0; _j < 4; ++_j) \
      acc[_i][_j] = __builtin_amdgcn_mfma_f32_16x16x32_bf16(af[_i], bf[_j], acc[_i][_j], 0, 0, 0); \
    __builtin_amdgcn_s_setprio(0); \
    __builtin_amdgcn_s_barrier(); }
#define PHB(bi) { const u16* _b = &lds[0][0] + (bi) * 16384; \
    _Pragma("unroll") for (int _i = 4; _i < 8; ++_i) af[_i] = *(const b16x8*)(_b + aoff + _i * 512); \
    __builtin_amdgcn_s_barrier(); \
    asm volatile("s_waitcnt lgkmcnt(0)" ::: "memory"); \
    __builtin_amdgcn_sched_barrier(0); \
    __builtin_amdgcn_s_setprio(1); \
    _Pragma("unroll") for (int _i = 4; _i < 8; ++_i) \
    _Pragma("unroll") for (int _j = 0; _j < 4; ++_j) \
      acc[_i][_j] = __builtin_amdgcn_mfma_f32_16x16x32_bf16(af[_i], bf[_j], acc[_i][_j], 0, 0, 0); \
    __builtin_amdgcn_s_setprio(0); }
#define WV(n) { asm volatile("s_waitcnt vmcnt(" #n ")" ::: "memory"); \
    __builtin_amdgcn_s_barrier(); asm volatile("" ::: "memory"); }

  STG_A(0) STG_B(0) STG_A(1) STG_B(1) STG_A(2) STG_B(2)
  asm volatile("s_waitcnt vmcnt(8)" ::: "memory");  // tile 0 landed; 1,2 in flight
  __builtin_amdgcn_s_barrier();
  asm volatile("" ::: "memory");

#pragma unroll 4
  for (int kt = 0; kt < 28; ++kt) {
    STG_A(kt + 3)
    PHA(kt & 3)
    STG_B(kt + 3)
    PHB(kt & 3)
    WV(8)             // tile kt+1 drained; kt+2,kt+3 (8 loads) in flight
  }
  STG_A(31) PHA(0) STG_B(31) PHB(0) WV(8)   // step 28
  PHA(1) PHB(1) WV(4)                       // step 29
  PHA(2) PHB(2) WV(0)                       // step 30
  PHA(3) PHB(3)                             // step 31
#undef STG_A
#undef STG_B
#undef PHA
#undef PHB
#undef WV

  if (MODE == 0) {
    const size_t G = 67108864;  // elements per q/k/v plane
    const int g = tn >> 10;     // 0:q 1:k 2:v (256 | 1024 -> uniform per block)
    const float* bias = (g == 0) ? b0 : (g == 1) ? b1 : b2;
    const int nn0 = (tn & 1023) + wc * 64;
#pragma unroll
    for (int j = 0; j < 4; ++j) {
      const int nn = nn0 + j * 16 + lo;
      const float bv = bias[nn];
      const int h = nn >> 5, hd = nn & 31;
      if (g < 2) {
#pragma unroll
        for (int i = 0; i < 8; ++i) {
          const int m0 = tm + wr * 128 + i * 16 + hi * 4;  // row = (l>>4)*4 + reg
          const int b = m0 >> 6, s0 = m0 & 63;
          const size_t base = (size_t)g * G + ((size_t)(b * 32 + h) * 64 + s0) * 32 + hd;
#pragma unroll
          for (int r = 0; r < 4; ++r) oq[base + (size_t)r * 32] = f2b(acc[i][j][r] + bv);
        }
      } else {
#pragma unroll
        for (int i = 0; i < 8; ++i) {
          const int m0 = tm + wr * 128 + i * 16 + hi * 4;
          const int b = m0 >> 6, s0 = m0 & 63;
          ushort4 pk;
          pk.x = f2b(acc[i][j][0] + bv);
          pk.y = f2b(acc[i][j][1] + bv);
          pk.z = f2b(acc[i][j][2] + bv);
          pk.w = f2b(acc[i][j][3] + bv);
          *(ushort4*)(oq + 2 * G + ((size_t)(b * 32 + h) * 32 + hd) * 64 + s0) = pk;
        }
      }
    }
  } else {
#pragma unroll
    for (int j = 0; j < 4; ++j) {
      const int n = tn + wc * 64 + j * 16 + lo;
      const float bv = b0[n];
#pragma unroll
      for (int i = 0; i < 8; ++i) {
        const int m0 = tm + wr * 128 + i * 16 + hi * 4;
#pragma unroll
        for (int r = 0; r < 4; ++r) of[(size_t)(m0 + r) * 1024 + n] = acc[i][j][r] + bv;
      }
    }
  }
}

// ---------------- attention (R11 = R8 structure + LDS-staged R-tables) ----------------
// One (b,h) per 256-thread block; wave w owns q-rows [w*16, w*16+16). R8 body (387 us
// measured): normal QK^T, per-row 16-lane softmax (shfl xor 1,2,4,8), packed b64 board
// stores, pl overlays board. NEW: Rq[h]/Rk[h] (7680 u16 each, pre-swizzled by k_rpe) are
// staged ONCE per block into LDS via 8 global_load_lds (was: every wave re-loading the
// whole 15KB table from L2 -> 120KB L2 traffic/block, ~40 VMEM instr/wave). Fragment
// reads become one ds_read_b128 at nt*512 + slotoff (involution; ~2-way banks).
__global__ __launch_bounds__(256) void k_attn(
    const u16* __restrict__ qkv, const u16* __restrict__ rq,
    const u16* __restrict__ rk, u16* __restrict__ att) {
  __shared__ alignas(16) u16 tab[2][7680];         // staged Rq / Rk (30720 B)
  __shared__ alignas(16) u16 board[16 * 240 * 4];  // 30720 B; pl overlays first 9216 B
  u16* pl = board;                                 // [64][72] row-major
  const int tid = threadIdx.x;
  const int l = tid & 63, w = tid >> 6;
  const int lo = l & 15, hi = l >> 4;
  const int b = blockIdx.x, h = blockIdx.y;
  const size_t G = 67108864;
  const u16* qp = qkv + (size_t)(b * 32 + h) * 2048;          // [64][32]
  const u16* kp = qkv + G + (size_t)(b * 32 + h) * 2048;      // [64][32]
  const u16* vp = qkv + 2 * G + (size_t)(b * 32 + h) * 2048;  // V^T [32][64]

  // stage both tables: 7680 u16 = 3 full (256 thr x 8 u16) + 1 tail (192 thr) instructions
  const u16* gq = rq + (size_t)h * 7680;
  const u16* gk = rk + (size_t)h * 7680;
#pragma unroll
  for (int i = 0; i < 3; ++i) {
    gl2lds16(gq + i * 2048 + tid * 8, &tab[0][0] + i * 2048 + tid * 8);
    gl2lds16(gk + i * 2048 + tid * 8, &tab[1][0] + i * 2048 + tid * 8);
  }
  if (tid < 192) {
    gl2lds16(gq + 6144 + tid * 8, &tab[0][0] + 6144 + tid * 8);
    gl2lds16(gk + 6144 + tid * 8, &tab[1][0] + 6144 + tid * 8);
  }

  // fragment-read lane constant for the swizzled tables (addr = nt*512 + slotoff)
  const int slotoff = (lo >> 1) * 64 + (((((lo & 1) << 2) + hi) ^ ((lo >> 1) & 7)) << 3);

  // Q fragment (A-operand): rows w*16+lo, d = hi*8..+8
  b16x8 qf = *(const b16x8*)(qp + (w * 16 + lo) * 32 + hi * 8);
  // hoisted V fragments (used phase 8)
  b16x8 v00 = *(const b16x8*)(vp + lo * 64 + hi * 8);
  b16x8 v01 = *(const b16x8*)(vp + lo * 64 + 32 + hi * 8);
  b16x8 v10 = *(const b16x8*)(vp + (16 + lo) * 64 + hi * 8);
  b16x8 v11 = *(const b16x8*)(vp + (16 + lo) * 64 + 32 + hi * 8);
  b16x8 kfa = *(const b16x8*)(kp + (w * 16 + lo) * 32 + hi * 8);

  // Phase 1: QK^T  (B-operand: lane holds K[kt*16+lo][d contiguous])
  f32x4 s0[4];
#pragma unroll
  for (int kt = 0; kt < 4; ++kt) {
    b16x8 kf = *(const b16x8*)(kp + (kt * 16 + lo) * 32 + hi * 8);
    f32x4 z = (f32x4){0.f, 0.f, 0.f, 0.f};
    s0[kt] = __builtin_amdgcn_mfma_f32_16x16x32_bf16(qf, kf, z, 0, 0, 0);
  }

  // tables resident for all waves before first table read
  asm volatile("s_waitcnt vmcnt(0)" ::: "memory");
  __syncthreads();

  // Phase 2: Bq = Q @ Rq[h]^T -> board rows (w*4+hi), packed b64 stores (wave-private rows)
#pragma unroll
  for (int nt = 0; nt < 15; ++nt) {
    b16x8 rf = *(const b16x8*)(&tab[0][0] + nt * 512 + slotoff);
    f32x4 z = (f32x4){0.f, 0.f, 0.f, 0.f};
    f32x4 c = __builtin_amdgcn_mfma_f32_16x16x32_bf16(qf, rf, z, 0, 0, 0);
    ushort4 pk;
    pk.x = f2b(c[0]); pk.y = f2b(c[1]); pk.z = f2b(c[2]); pk.w = f2b(c[3]);
    *(ushort4*)(board + (((w * 4 + hi) * 240 + nt * 16 + lo) << 2)) = pk;
  }
  // Phase 3: gather Bq (reads only this wave's rows; same-wave LDS RAW -> lgkmcnt)
#pragma unroll
  for (int kt = 0; kt < 4; ++kt)
#pragma unroll
    for (int r = 0; r < 4; ++r) {
      int q = w * 16 + hi * 4 + r, k = kt * 16 + lo;
      int rel = 15 * ((q >> 3) - (k >> 3) + 7) + (q & 7) - (k & 7) + 7;
      s0[kt][r] += b2f(board[((w * 4 + hi) * 240 + rel) * 4 + r]);
    }

  // Phase 4: Bk = K @ Rk[h]^T -> board rows (w*4+hi) (overwrites own rows only)
#pragma unroll
  for (int nt = 0; nt < 15; ++nt) {
    b16x8 rf = *(const b16x8*)(&tab[1][0] + nt * 512 + slotoff);
    f32x4 z = (f32x4){0.f, 0.f, 0.f, 0.f};
    f32x4 c = __builtin_amdgcn_mfma_f32_16x16x32_bf16(kfa, rf, z, 0, 0, 0);
    ushort4 pk;
    pk.x = f2b(c[0]); pk.y = f2b(c[1]); pk.z = f2b(c[2]); pk.w = f2b(c[3]);
    *(ushort4*)(board + (((w * 4 + hi) * 240 + nt * 16 + lo) << 2)) = pk;
  }
  __syncthreads();  // Bk board read cross-wave below
  // Phase 5: gather Bk (indexed by k row -> all rows)
#pragma unroll
  for (int kt = 0; kt < 4; ++kt)
#pragma unroll
    for (int r = 0; r < 4; ++r) {
      int q = w * 16 + hi * 4 + r, k = kt * 16 + lo;
      int rel = 15 * ((q >> 3) - (k >> 3) + 7) + (q & 7) - (k & 7) + 7;
      s0[kt][r] += b2f(board[((k >> 2) * 240 + rel) * 4 + (k & 3)]);
    }

  // Phase 6: scale + softmax (rows live in 16-lane groups; reduce over xor 1,2,4,8)
  const float sc = 0.17677669529663689f;  // 1/sqrt(32)
#pragma unroll
  for (int kt = 0; kt < 4; ++kt) s0[kt] *= sc;
  float p[4][4], rsum[4];
#pragma unroll
  for (int r = 0; r < 4; ++r) {
    float m = s0[0][r];
    m = fmaxf(m, s0[1][r]); m = fmaxf(m, s0[2][r]); m = fmaxf(m, s0[3][r]);
    m = fmaxf(m, __shfl_xor(m, 1));
    m = fmaxf(m, __shfl_xor(m, 2));
    m = fmaxf(m, __shfl_xor(m, 4));
    m = fmaxf(m, __shfl_xor(m, 8));
    float sum = 0.f;
#pragma unroll
    for (int kt = 0; kt < 4; ++kt) {
      float e = __expf(s0[kt][r] - m);
      p[kt][r] = e;
      sum += e;
    }
    sum += __shfl_xor(sum, 1);
    sum += __shfl_xor(sum, 2);
    sum += __shfl_xor(sum, 4);
    sum += __shfl_xor(sum, 8);
    rsum[r] = 1.f / sum;
  }

  __syncthreads();  // overlay guard: all board gathers done before pl overwrites board bytes

  // Phase 7: P -> LDS (wave-private rows; normalization deferred to output)
#pragma unroll
  for (int kt = 0; kt < 4; ++kt)
#pragma unroll
    for (int r = 0; r < 4; ++r) pl[(w * 16 + hi * 4 + r) * 72 + kt * 16 + lo] = f2b(p[kt][r]);

  // Phase 8: O = P @ V   (A: P rows w*16+lo; B: V^T rows hd, k contiguous)
  f32x4 o0 = (f32x4){0.f, 0.f, 0.f, 0.f}, o1 = (f32x4){0.f, 0.f, 0.f, 0.f};
  {
    b16x8 pa0 = *(const b16x8*)(pl + (w * 16 + lo) * 72 + hi * 8);
    b16x8 pa1 = *(const b16x8*)(pl + (w * 16 + lo) * 72 + 32 + hi * 8);
    o0 = __builtin_amdgcn_mfma_f32_16x16x32_bf16(pa0, v00, o0, 0, 0, 0);
    o1 = __builtin_amdgcn_mfma_f32_16x16x32_bf16(pa0, v10, o1, 0, 0, 0);
    o0 = __builtin_amdgcn_mfma_f32_16x16x32_bf16(pa1, v01, o0, 0, 0, 0);
    o1 = __builtin_amdgcn_mfma_f32_16x16x32_bf16(pa1, v11, o1, 0, 0, 0);
  }

  // Phase 9: write att[b][s][h*32+hd] (bf16), scaled by 1/rowsum
#pragma unroll
  for (int r = 0; r < 4; ++r) {
    int q = w * 16 + hi * 4 + r;
    size_t base = (size_t)(b * 64 + q) * 1024 + h * 32;
    att[base + lo] = f2b(o0[r] * rsum[r]);
    att[base + 16 + lo] = f2b(o1[r] * rsum[r]);
  }
}

extern "C" void kernel_launch(void* const* d_in, const int* in_sizes, int n_in,
                              void* d_out, int out_size, void* d_ws, size_t ws_size,
                              hipStream_t stream) {
  const float* x   = (const float*)d_in[0];
  const float* qw  = (const float*)d_in[1];
  const float* qb  = (const float*)d_in[2];
  const float* kw  = (const float*)d_in[3];
  const float* kb  = (const float*)d_in[4];
  const float* vw  = (const float*)d_in[5];
  const float* vb  = (const float*)d_in[6];
  const float* ow  = (const float*)d_in[7];
  const float* ob  = (const float*)d_in[8];
  const float* rqw = (const float*)d_in[9];
  const float* rkw = (const float*)d_in[10];

  // workspace layout (total 680,460,288 bytes)
  if (ws_size < 680460288ULL) return;  // diagnostic: leaves d_out zeroed -> absmax == max|ref|
  char* p = (char*)d_ws;
  u16* ws_x   = (u16*)p; p += (size_t)65536 * 1024 * 2;      // x bf16
  u16* ws_w   = (u16*)p; p += (size_t)3 * 1024 * 1024 * 2;   // qkv weights bf16 [3072][1024]
  u16* ws_wo  = (u16*)p; p += (size_t)1024 * 1024 * 2;       // out_w bf16
  u16* ws_rq  = (u16*)p; p += (size_t)32 * 7680 * 2;         // Rq swizzled [h][7680]
  u16* ws_rk  = (u16*)p; p += (size_t)32 * 7680 * 2;         // Rk swizzled [h][7680]
  u16* ws_qkv = (u16*)p; p += (size_t)3 * 67108864 * 2;      // q,k [b][h][s][hd]; v [b][h][hd][s]
  u16* ws_att = (u16*)p; p += (size_t)65536 * 1024 * 2;      // attention out [b*s][1024]

  k_cvt<<<32768, 256, 0, stream>>>(x, ws_x, 67108864L);
  k_cvt<<<512, 256, 0, stream>>>(qw, ws_w, 1048576L);
  k_cvt<<<512, 256, 0, stream>>>(kw, ws_w + 1048576, 1048576L);
  k_cvt<<<512, 256, 0, stream>>>(vw, ws_w + 2097152, 1048576L);
  k_cvt<<<512, 256, 0, stream>>>(ow, ws_wo, 1048576L);
  k_rpe<<<dim3(30, 32, 2), 256, 0, stream>>>(rqw, rkw, ws_rq, ws_rk);

  // QKV projection, split into two half-M launches (profiling visibility; nwg=1536 %8==0)
  k_gemm<0><<<dim3(12, 128), 512, 0, stream>>>(ws_x, ws_w, qb, kb, vb, ws_qkv, nullptr, 0);
  k_gemm<0><<<dim3(12, 128), 512, 0, stream>>>(ws_x, ws_w, qb, kb, vb, ws_qkv, nullptr, 32768);
  // attention: grid.x = b (fastest) so consecutive blocks reuse Rq[h]/Rk[h] in cache
  k_attn<<<dim3(1024, 32), 256, 0, stream>>>(ws_qkv, ws_rq, ws_rk, ws_att);
  // output projection: 4 n-tiles x 256 m-tiles (nwg=1024)
  k_gemm<1><<<dim3(4, 256), 512, 0, stream>>>(ws_att, ws_wo, ob, nullptr, nullptr, nullptr,
                                              (float*)d_out, 0);
}